// Round 1
// baseline (450.529 us; speedup 1.0000x reference)
//
#include <hip/hip_runtime.h>

// NCC loss: 1 - mean( cross^2 / (pvar*tvar + 1e-8) ) over 9^3 zero-padded
// box windows, input (4,1,160,160,160) fp32.
//
// Strategy: fully fused single pass. Block = 16x16 xy output tile, 40-deep
// z chunk. Threads own input columns (24x24 halo tile) and keep sliding
// z-window sums of {p,t,p2,t2,pt} in registers; per z-step the 2D 9x9 box
// sum is done in LDS with separable running-sum passes; cc accumulated in
// registers, block-reduced, atomicAdd to ws; finalize kernel writes scalar.

#define DSZ   160
#define NBATCH 4
#define RAD   4
#define WINSZ 9
#define TX    16
#define TY    16
#define IX    (TX + 2*RAD)     // 24
#define IY    (TY + 2*RAD)     // 24
#define NCOL  (IX*IY)          // 576
#define ZCHUNK 40
#define NZC   (DSZ/ZCHUNK)     // 4
#define SLICE (DSZ*DSZ)        // 25600
#define VOL   (DSZ*DSZ*DSZ)    // 4096000
#define WINV  (1.0f/729.0f)
#define NVOX_INV (1.0f/16384000.0f)

__global__ __launch_bounds__(256)
void ncc_main(const float* __restrict__ pred, const float* __restrict__ tgt,
              float* __restrict__ accum)
{
    const int tid   = threadIdx.x;
    const int ox    = blockIdx.x * TX;
    const int oy    = blockIdx.y * TY;
    const int batch = blockIdx.z >> 2;
    const int z0    = (blockIdx.z & 3) * ZCHUNK;

    __shared__ float s1[5][IY][IX+1];   // z-window column sums (+halo)
    __shared__ float s2[5][IY][TX+1];   // after x sliding pass
    __shared__ float s3[5][TY][TX];     // after y sliding pass (full 3D sums)
    __shared__ float red[4];

    // Column assignment: up to 3 columns per thread (576 cols / 256 threads).
    float zs0[3], zs1[3], zs2[3], zs3[3], zs4[3];
    int   cbase[3], ccx[3], ccy[3];
    bool  cvalid[3], cin[3];
    #pragma unroll
    for (int j = 0; j < 3; ++j) {
        zs0[j]=zs1[j]=zs2[j]=zs3[j]=zs4[j]=0.f;
        int c = tid + j*256;
        bool inr = (c < NCOL);
        int cy = 0, cx = 0, gx = 0, gy = 0;
        bool v = false;
        if (inr) {
            cy = c / IX; cx = c - cy*IX;
            gx = ox - RAD + cx; gy = oy - RAD + cy;
            v = (gx >= 0 && gx < DSZ && gy >= 0 && gy < DSZ);
        }
        cin[j] = inr; cvalid[j] = v;
        ccx[j] = cx; ccy[j] = cy;
        cbase[j] = batch*VOL + gy*DSZ + gx;
    }

    float acc = 0.f;

    // Warm-up: pre-add slices [z0-4, z0+3]
    for (int z = z0 - RAD; z < z0 + RAD; ++z) {
        if (z < 0 || z >= DSZ) continue;
        #pragma unroll
        for (int j = 0; j < 3; ++j) if (cvalid[j]) {
            int off = cbase[j] + z*SLICE;
            float p = pred[off], t = tgt[off];
            zs0[j]+=p; zs1[j]+=t; zs2[j]+=p*p; zs3[j]+=t*t; zs4[j]+=p*t;
        }
    }

    for (int zo = z0; zo < z0 + ZCHUNK; ++zo) {
        // slide z window: add slice zo+4, subtract slice zo-5
        int za = zo + RAD;
        if (za < DSZ) {
            #pragma unroll
            for (int j = 0; j < 3; ++j) if (cvalid[j]) {
                int off = cbase[j] + za*SLICE;
                float p = pred[off], t = tgt[off];
                zs0[j]+=p; zs1[j]+=t; zs2[j]+=p*p; zs3[j]+=t*t; zs4[j]+=p*t;
            }
        }
        int zsub = zo - RAD - 1;
        if (zsub >= 0 && zsub >= z0 - RAD) {
            #pragma unroll
            for (int j = 0; j < 3; ++j) if (cvalid[j]) {
                int off = cbase[j] + zsub*SLICE;
                float p = pred[off], t = tgt[off];
                zs0[j]-=p; zs1[j]-=t; zs2[j]-=p*p; zs3[j]-=t*t; zs4[j]-=p*t;
            }
        }

        // stage z-sums to LDS (OOB columns contribute zeros)
        #pragma unroll
        for (int j = 0; j < 3; ++j) if (cin[j]) {
            s1[0][ccy[j]][ccx[j]] = zs0[j];
            s1[1][ccy[j]][ccx[j]] = zs1[j];
            s1[2][ccy[j]][ccx[j]] = zs2[j];
            s1[3][ccy[j]][ccx[j]] = zs3[j];
            s1[4][ccy[j]][ccx[j]] = zs4[j];
        }
        __syncthreads();

        // x-pass: 5 fields x 24 rows = 120 tasks, sliding 9-window
        if (tid < 5*IY) {
            int q = tid / IY, row = tid - q*IY;
            float run = 0.f;
            #pragma unroll
            for (int k = 0; k < WINSZ-1; ++k) run += s1[q][row][k];
            #pragma unroll
            for (int x = 0; x < TX; ++x) {
                run += s1[q][row][x + WINSZ - 1];
                s2[q][row][x] = run;
                run -= s1[q][row][x];
            }
        }
        __syncthreads();

        // y-pass: 5 fields x 16 cols = 80 tasks, sliding 9-window
        if (tid < 5*TX) {
            int q = tid / TX, x = tid - q*TX;
            float run = 0.f;
            #pragma unroll
            for (int k = 0; k < WINSZ-1; ++k) run += s2[q][k][x];
            #pragma unroll
            for (int y = 0; y < TY; ++y) {
                run += s2[q][y + WINSZ - 1][x];
                s3[q][y][x] = run;
                run -= s2[q][y][x];
            }
        }
        __syncthreads();

        // cc per output voxel (one per thread)
        {
            int y = tid >> 4, x = tid & 15;
            float Sp  = s3[0][y][x], St  = s3[1][y][x];
            float Spp = s3[2][y][x], Stt = s3[3][y][x], Spt = s3[4][y][x];
            float cross = Spt - Sp*St*WINV;
            float pv    = Spp - Sp*Sp*WINV;
            float tv    = Stt - St*St*WINV;
            float cc    = cross*cross / (pv*tv + 1e-8f);
            acc += cc;
        }
        // no sync needed: next writer of s3 is behind two barriers
    }

    // block reduction -> one atomic per block
    float v = acc;
    #pragma unroll
    for (int off = 32; off > 0; off >>= 1) v += __shfl_down(v, off, 64);
    if ((tid & 63) == 0) red[tid >> 6] = v;
    __syncthreads();
    if (tid == 0) atomicAdd(accum, red[0]+red[1]+red[2]+red[3]);
}

__global__ void ncc_final(const float* __restrict__ accum, float* __restrict__ out)
{
    out[0] = 1.0f - accum[0] * NVOX_INV;
}

extern "C" void kernel_launch(void* const* d_in, const int* in_sizes, int n_in,
                              void* d_out, int out_size, void* d_ws, size_t ws_size,
                              hipStream_t stream)
{
    const float* pred = (const float*)d_in[0];
    const float* tgt  = (const float*)d_in[1];
    float* out = (float*)d_out;
    float* ws  = (float*)d_ws;

    hipMemsetAsync(ws, 0, sizeof(float), stream);
    dim3 grid(DSZ/TX, DSZ/TY, NBATCH*NZC);   // 10 x 10 x 16 = 1600 blocks
    ncc_main<<<grid, 256, 0, stream>>>(pred, tgt, ws);
    ncc_final<<<1, 1, 0, stream>>>(ws, out);
}

// Round 2
// 313.019 us; speedup vs baseline: 1.4393x; 1.4393x over previous
//
#include <hip/hip_runtime.h>

// NCC loss: 1 - mean( cross^2 / (pvar*tvar + 1e-8) ) over 9^3 zero-padded
// box windows, input (4,1,160,160,160) fp32.
//
// R2: software-pipelined slice prefetch (hides L3-hit latency of the
// add/subtract slice loads), 2 barriers per z-step instead of 3 (y-pass
// fused into per-voxel cc: 9-tap per thread), x-pass widened to 240
// threads. LDS 25.6 -> 20.2 KB.

#define DSZ   160
#define NBATCH 4
#define RAD   4
#define WINSZ 9
#define TX    16
#define TY    16
#define IX    (TX + 2*RAD)     // 24
#define IY    (TY + 2*RAD)     // 24
#define NCOL  (IX*IY)          // 576
#define ZCHUNK 40
#define NZC   (DSZ/ZCHUNK)     // 4
#define SLICE (DSZ*DSZ)        // 25600
#define VOL   (DSZ*DSZ*DSZ)    // 4096000
#define WINV  (1.0f/729.0f)
#define NVOX_INV (1.0f/16384000.0f)

__global__ __launch_bounds__(256)
void ncc_main(const float* __restrict__ pred, const float* __restrict__ tgt,
              float* __restrict__ accum)
{
    const int tid   = threadIdx.x;
    const int ox    = blockIdx.x * TX;
    const int oy    = blockIdx.y * TY;
    const int batch = blockIdx.z >> 2;
    const int z0    = (blockIdx.z & 3) * ZCHUNK;

    __shared__ float s1[5][IY][IX+1];   // z-window column sums (+halo), pad 25
    __shared__ float s2[5][IY][TX+1];   // after x sliding pass, pad 17
    __shared__ float red[4];

    // Column assignment: up to 3 columns per thread (576 cols / 256 threads).
    float zs0[3], zs1[3], zs2[3], zs3[3], zs4[3];
    int   cbase[3], ccx[3], ccy[3];
    bool  cvalid[3], cin[3];
    #pragma unroll
    for (int j = 0; j < 3; ++j) {
        zs0[j]=zs1[j]=zs2[j]=zs3[j]=zs4[j]=0.f;
        int c = tid + j*256;
        bool inr = (c < NCOL);
        int cy = 0, cx = 0, gx = 0, gy = 0;
        bool v = false;
        if (inr) {
            cy = c / IX; cx = c - cy*IX;
            gx = ox - RAD + cx; gy = oy - RAD + cy;
            v = (gx >= 0 && gx < DSZ && gy >= 0 && gy < DSZ);
        }
        cin[j] = inr; cvalid[j] = v;
        ccx[j] = cx; ccy[j] = cy;
        cbase[j] = batch*VOL + gy*DSZ + gx;
    }

    float acc = 0.f;

    // Warm-up: pre-add slices [z0-4, z0+3]
    for (int z = z0 - RAD; z < z0 + RAD; ++z) {
        if (z < 0 || z >= DSZ) continue;
        #pragma unroll
        for (int j = 0; j < 3; ++j) if (cvalid[j]) {
            int off = cbase[j] + z*SLICE;
            float p = pred[off], t = tgt[off];
            zs0[j]+=p; zs1[j]+=t; zs2[j]+=p*p; zs3[j]+=t*t; zs4[j]+=p*t;
        }
    }

    // Prefetch registers for the next z-step's add/sub slices.
    float pa[3], ta[3], psb[3], tsb[3];

    // issue prefetch for z-step `zo`
    auto prefetch = [&](int zo) {
        int zadd = zo + RAD;
        int zsub = zo - RAD - 1;
        bool va = (zadd < DSZ);
        bool vs = (zsub >= 0) && (zsub >= z0 - RAD);
        #pragma unroll
        for (int j = 0; j < 3; ++j) {
            pa[j]=ta[j]=psb[j]=tsb[j]=0.f;
            if (cvalid[j] && va) {
                int off = cbase[j] + zadd*SLICE;
                pa[j] = pred[off]; ta[j] = tgt[off];
            }
            if (cvalid[j] && vs) {
                int off = cbase[j] + zsub*SLICE;
                psb[j] = pred[off]; tsb[j] = tgt[off];
            }
        }
    };

    prefetch(z0);

    for (int zo = z0; zo < z0 + ZCHUNK; ++zo) {
        // fold prefetched add/sub slices into the z-window sums
        #pragma unroll
        for (int j = 0; j < 3; ++j) {
            float p = pa[j],  t = ta[j];
            float q = psb[j], u = tsb[j];
            zs0[j] += p - q;
            zs1[j] += t - u;
            zs2[j] += p*p - q*q;
            zs3[j] += t*t - u*u;
            zs4[j] += p*t - q*u;
        }

        // stage z-sums to LDS (OOB columns contribute zeros)
        #pragma unroll
        for (int j = 0; j < 3; ++j) if (cin[j]) {
            s1[0][ccy[j]][ccx[j]] = zs0[j];
            s1[1][ccy[j]][ccx[j]] = zs1[j];
            s1[2][ccy[j]][ccx[j]] = zs2[j];
            s1[3][ccy[j]][ccx[j]] = zs3[j];
            s1[4][ccy[j]][ccx[j]] = zs4[j];
        }

        // issue next step's global loads: they complete behind the barriers
        if (zo + 1 < z0 + ZCHUNK) prefetch(zo + 1);

        __syncthreads();   // barrier A: s1 ready (also protects s2 reuse)

        // x-pass: 5 fields x 24 rows x 2 halves = 240 tasks, sliding 9-window
        if (tid < 240) {
            int q    = tid / 48;
            int r2   = tid - q*48;
            int row  = r2 >> 1;
            int x0   = (r2 & 1) * 8;
            float run = 0.f;
            #pragma unroll
            for (int k = 0; k < 8; ++k) run += s1[q][row][x0 + k];
            #pragma unroll
            for (int i = 0; i < 8; ++i) {
                run += s1[q][row][x0 + i + 8];
                s2[q][row][x0 + i] = run;
                run -= s1[q][row][x0 + i];
            }
        }
        __syncthreads();   // barrier B: s2 ready (also ends s1 reads)

        // fused y-pass + cc: each thread 9-taps its own output voxel
        {
            int y = tid >> 4, x = tid & 15;
            float S0=0.f,S1=0.f,S2=0.f,S3=0.f,S4=0.f;
            #pragma unroll
            for (int k = 0; k < WINSZ; ++k) {
                S0 += s2[0][y+k][x];
                S1 += s2[1][y+k][x];
                S2 += s2[2][y+k][x];
                S3 += s2[3][y+k][x];
                S4 += s2[4][y+k][x];
            }
            float cross = S4 - S0*S1*WINV;
            float pv    = S2 - S0*S0*WINV;
            float tv    = S3 - S1*S1*WINV;
            acc += cross*cross / (pv*tv + 1e-8f);
        }
        // next iteration's barrier A protects s2 against the next x-pass
    }

    // block reduction -> one atomic per block
    float v = acc;
    #pragma unroll
    for (int off = 32; off > 0; off >>= 1) v += __shfl_down(v, off, 64);
    if ((tid & 63) == 0) red[tid >> 6] = v;
    __syncthreads();
    if (tid == 0) atomicAdd(accum, red[0]+red[1]+red[2]+red[3]);
}

__global__ void ncc_final(const float* __restrict__ accum, float* __restrict__ out)
{
    out[0] = 1.0f - accum[0] * NVOX_INV;
}

extern "C" void kernel_launch(void* const* d_in, const int* in_sizes, int n_in,
                              void* d_out, int out_size, void* d_ws, size_t ws_size,
                              hipStream_t stream)
{
    const float* pred = (const float*)d_in[0];
    const float* tgt  = (const float*)d_in[1];
    float* out = (float*)d_out;
    float* ws  = (float*)d_ws;

    hipMemsetAsync(ws, 0, sizeof(float), stream);
    dim3 grid(DSZ/TX, DSZ/TY, NBATCH*NZC);   // 10 x 10 x 16 = 1600 blocks
    ncc_main<<<grid, 256, 0, stream>>>(pred, tgt, ws);
    ncc_final<<<1, 1, 0, stream>>>(ws, out);
}

// Round 3
// 244.504 us; speedup vs baseline: 1.8426x; 1.2802x over previous
//
#include <hip/hip_runtime.h>

// NCC loss: 1 - mean( cross^2 / (pvar*tvar + 1e-8) ) over 9^3 zero-padded
// box windows, input (4,1,160,160,160) fp32.
//
// R3: LDS-pipe was the bottleneck (R2: ~1700 LDS-pipe cyc/block-step ~ 100%
// busy). Changes:
//  - x-direction 9-sum computed IN REGISTERS with DPP row_shl:1/2 cross-lane
//    shifts (lane = row*8 + xgroup; group = 4 cols). s1 staging deleted.
//  - subtract slices come from a thread-private LDS ring (9 slots), so each
//    global slice is fetched once: FETCH 624 -> ~355 MB.
//  - s2 is field-major [5][24][20] (row pad 20): fused y+cc 12-tap reads are
//    exactly 2-way bank aliased = free; float4 writes.
//  - block 192 = 3 waves; LDS 51 KB -> 3 blocks/CU.

#define DSZ    160
#define NBATCH 4
#define RAD    4
#define TX     16
#define TY     16
#define ZCHUNK 40
#define NZC    (DSZ/ZCHUNK)    // 4
#define SLICE  (DSZ*DSZ)
#define VOL    (DSZ*DSZ*DSZ)
#define WINV   (1.0f/729.0f)
#define NVOX_INV (1.0f/16384000.0f)

#define NROW 24        // halo rows per tile
#define NGRP 6         // x groups of 4 halo cols (24)
#define TPR  8         // lanes per row (6 active)
#define BLK  192
#define NSTG 144       // staging threads

#define S2_RS 20                // s2 row stride (16 outputs + pad)
#define S2_FS (NROW*S2_RS)      // 480 floats per field

__device__ __forceinline__ float dpp_shl1(float x) {  // lane i <- lane i+1 (16-lane row, OOB=0)
    return __int_as_float(__builtin_amdgcn_update_dpp(0, __float_as_int(x), 0x101, 0xf, 0xf, true));
}
__device__ __forceinline__ float dpp_shl2(float x) {  // lane i <- lane i+2
    return __int_as_float(__builtin_amdgcn_update_dpp(0, __float_as_int(x), 0x102, 0xf, 0xf, true));
}

__global__ __launch_bounds__(BLK)
void ncc_main(const float* __restrict__ pred, const float* __restrict__ tgt,
              float* __restrict__ accum)
{
    const int tid = threadIdx.x;
    const int row = tid >> 3;      // 0..23 halo row
    const int g   = tid & 7;       // 0..7; g<6 = active x-group
    const int ox  = blockIdx.x * TX;
    const int oy  = blockIdx.y * TY;
    const int batch = blockIdx.z >> 2;
    const int z0  = (blockIdx.z & 3) * ZCHUNK;

    __shared__ float s2[5*S2_FS];        // 9.6 KB, field-major
    __shared__ float ring[9*NSTG*8];     // 41.5 KB, [slot][st][p0..3,t0..3]

    const bool stg = (g < NGRP);
    const int  gy  = oy - RAD + row;
    const int  gx0 = ox - RAD + g*4;
    const bool ldok = stg && (gy >= 0) && (gy < DSZ) && (gx0 >= 0) && (gx0 + 3 < DSZ);
    const int  base = batch*VOL + gy*DSZ + gx0;     // only used under ldok
    const int  st   = row*NGRP + g;                 // staging index (stg only)

    // z-window sums for own 4 columns x 5 fields, in registers
    float zs[5][4];
    #pragma unroll
    for (int f = 0; f < 5; ++f)
        #pragma unroll
        for (int j = 0; j < 4; ++j) zs[f][j] = 0.f;

    // ---- warm-up: slices [z0-4, z0+3] -> fold add + store raw to ring ----
    for (int z = z0 - RAD; z < z0 + RAD; ++z) {
        if (z < 0) continue;
        float4 p4 = {0,0,0,0}, t4 = {0,0,0,0};
        if (ldok) {
            p4 = *(const float4*)(pred + base + z*SLICE);
            t4 = *(const float4*)(tgt  + base + z*SLICE);
        }
        if (stg) {
            const float pc[4] = {p4.x,p4.y,p4.z,p4.w};
            const float tc[4] = {t4.x,t4.y,t4.z,t4.w};
            #pragma unroll
            for (int j = 0; j < 4; ++j) {
                zs[0][j] += pc[j];        zs[1][j] += tc[j];
                zs[2][j] += pc[j]*pc[j];  zs[3][j] += tc[j]*tc[j];
                zs[4][j] += pc[j]*tc[j];
            }
            float4* w4 = (float4*)&ring[((z % 9)*NSTG + st)*8];
            w4[0] = p4; w4[1] = t4;
        }
    }

    // ---- prefetch of the add slice (z = zo+4) ----
    float4 pa4 = {0,0,0,0}, ta4 = {0,0,0,0};
    auto pf = [&](int zo) {
        int za = zo + RAD;
        float4 p = {0,0,0,0}, t = {0,0,0,0};
        if (ldok && za < DSZ) {
            p = *(const float4*)(pred + base + za*SLICE);
            t = *(const float4*)(tgt  + base + za*SLICE);
        }
        pa4 = p; ta4 = t;
    };
    if (stg) pf(z0);

    float acc = 0.f;

    for (int zo = z0; zo < z0 + ZCHUNK; ++zo) {
        if (stg) {
            // subtract slice zo-5 from ring (loaded 9 steps ago)
            int zsub = zo - 5;
            if (zsub >= 0 && zsub >= z0 - RAD) {
                const float4* r4 = (const float4*)&ring[((zsub % 9)*NSTG + st)*8];
                float4 ps = r4[0], ts = r4[1];
                const float pc[4] = {ps.x,ps.y,ps.z,ps.w};
                const float tc[4] = {ts.x,ts.y,ts.z,ts.w};
                #pragma unroll
                for (int j = 0; j < 4; ++j) {
                    zs[0][j] -= pc[j];        zs[1][j] -= tc[j];
                    zs[2][j] -= pc[j]*pc[j];  zs[3][j] -= tc[j]*tc[j];
                    zs[4][j] -= pc[j]*tc[j];
                }
            }
            // add prefetched slice zo+4; store raw to ring (same slot, after read)
            {
                const float pc[4] = {pa4.x,pa4.y,pa4.z,pa4.w};
                const float tc[4] = {ta4.x,ta4.y,ta4.z,ta4.w};
                #pragma unroll
                for (int j = 0; j < 4; ++j) {
                    zs[0][j] += pc[j];        zs[1][j] += tc[j];
                    zs[2][j] += pc[j]*pc[j];  zs[3][j] += tc[j]*tc[j];
                    zs[4][j] += pc[j]*tc[j];
                }
                int za = zo + RAD;
                if (za < DSZ) {
                    float4* w4 = (float4*)&ring[((za % 9)*NSTG + st)*8];
                    w4[0] = pa4; w4[1] = ta4;
                }
            }

            // x 9-sum in registers via group prefix + DPP neighbor fetch
            #pragma unroll
            for (int f = 0; f < 5; ++f) {
                float P0 = zs[f][0];
                float P1 = P0 + zs[f][1];
                float P2 = P1 + zs[f][2];
                float P3 = P2 + zs[f][3];
                float T  = dpp_shl1(P3);   // full sum of group g+1
                float Q0 = dpp_shl2(P0);   // prefixes of group g+2
                float Q1 = dpp_shl2(P1);
                float Q2 = dpp_shl2(P2);
                float Q3 = dpp_shl2(P3);
                if (g < 4) {               // output groups 0..3 (x = 4g+i)
                    float b = P3 + T;
                    float4 o;
                    o.x = b + Q0;
                    o.y = b - P0 + Q1;
                    o.z = b - P1 + Q2;
                    o.w = b - P2 + Q3;
                    *(float4*)&s2[f*S2_FS + row*S2_RS + g*4] = o;
                }
            }

            // issue next step's global loads; they drain behind barrier A
            if (zo + 1 < z0 + ZCHUNK) pf(zo + 1);
        }
        __syncthreads();   // A: s2 ready

        // fused y 9-sum + cc: 64 tasks, each 4 voxels in a y-quarter
        if (tid < 64) {
            const int x  = tid & 15;
            const int yq = (tid >> 4) * 4;
            float S[5][4];
            #pragma unroll
            for (int f = 0; f < 5; ++f) {
                const float* col = &s2[f*S2_FS + x];
                float r0 = col[(yq+0)*S2_RS];
                float r1 = col[(yq+1)*S2_RS];
                float r2 = col[(yq+2)*S2_RS];
                float r3 = col[(yq+3)*S2_RS];
                float run = r0 + r1 + r2 + r3
                          + col[(yq+4)*S2_RS] + col[(yq+5)*S2_RS]
                          + col[(yq+6)*S2_RS] + col[(yq+7)*S2_RS];
                run += col[(yq+8)*S2_RS];  S[f][0] = run;
                run -= r0; run += col[(yq+9)*S2_RS];  S[f][1] = run;
                run -= r1; run += col[(yq+10)*S2_RS]; S[f][2] = run;
                run -= r2; run += col[(yq+11)*S2_RS]; S[f][3] = run;
            }
            #pragma unroll
            for (int i = 0; i < 4; ++i) {
                float Sp = S[0][i], St = S[1][i];
                float Spp = S[2][i], Stt = S[3][i], Spt = S[4][i];
                float cross = Spt - Sp*St*WINV;
                float pv    = Spp - Sp*Sp*WINV;
                float tv    = Stt - St*St*WINV;
                acc += cross*cross / (pv*tv + 1e-8f);
            }
        }
        __syncthreads();   // B: s2 consumed; next step may rewrite
    }

    // wave 0 holds all cc partials
    if (tid < 64) {
        float v = acc;
        #pragma unroll
        for (int off = 32; off > 0; off >>= 1) v += __shfl_down(v, off, 64);
        if (tid == 0) atomicAdd(accum, v);
    }
}

__global__ void ncc_final(const float* __restrict__ accum, float* __restrict__ out)
{
    out[0] = 1.0f - accum[0] * NVOX_INV;
}

extern "C" void kernel_launch(void* const* d_in, const int* in_sizes, int n_in,
                              void* d_out, int out_size, void* d_ws, size_t ws_size,
                              hipStream_t stream)
{
    const float* pred = (const float*)d_in[0];
    const float* tgt  = (const float*)d_in[1];
    float* out = (float*)d_out;
    float* ws  = (float*)d_ws;

    hipMemsetAsync(ws, 0, sizeof(float), stream);
    dim3 grid(DSZ/TX, DSZ/TY, NBATCH*NZC);   // 10 x 10 x 16 = 1600 blocks
    ncc_main<<<grid, BLK, 0, stream>>>(pred, tgt, ws);
    ncc_final<<<1, 1, 0, stream>>>(ws, out);
}